// Round 1
// baseline (1072.878 us; speedup 1.0000x reference)
//
#include <hip/hip_runtime.h>
#include <math.h>

#define BATCH 2
#define DIM 192
#define HIMG 192
#define WIMG 192
#define NPIX (HIMG*WIMG)      // 36864
#define HEADS 6
#define HC 32
#define NTOK 256
#define WDq 12
#define NWIN_B 144
#define NWIN (BATCH*NWIN_B)   // 288
#define RPE_N 961
#define SLABSZ ((size_t)NWIN*HEADS*NTOK*HC)   // 14,155,776 floats per q/k/v slab

// ---------------------------------------------------------------------------
// K1: qkv = w_qkv @ x + b_qkv, scattered into windowed layout.
//   q,k slabs: [win][head][t][c]   (c contiguous)
//   v slab   : [win][head][c][t]   (transposed, for future MFMA PV B-operand)
// grid (576 hw-tiles, 3 slabs, 2 batch), block 256.
// Block tile: 192 o x 64 hw, K-chunks of 32. Thread tile 12 o x 4 hw.
// ---------------------------------------------------------------------------
__global__ __launch_bounds__(256)
void k_qkv(const float* __restrict__ x, const float* __restrict__ wqkv,
           const float* __restrict__ bqkv, float* __restrict__ qkv) {
  const int hw0 = blockIdx.x * 64;
  const int slab = blockIdx.y;
  const int b = blockIdx.z;
  __shared__ float lw[32][196];   // [k][o], pad 196 -> 4-bank stagger, 16B aligned rows
  __shared__ float lx[32][64];    // [k][hw]
  const int tid = threadIdx.x;
  const int ti = tid & 15;        // o-thread
  const int tj = tid >> 4;        // hw-thread
  float acc[12][4];
  #pragma unroll
  for (int r = 0; r < 12; ++r)
    #pragma unroll
    for (int s = 0; s < 4; ++s) acc[r][s] = 0.f;

  const float* xb = x + (size_t)b*DIM*NPIX + hw0;
  const float* wb = wqkv + (size_t)slab*DIM*DIM;

  #pragma unroll 1
  for (int k0 = 0; k0 < DIM; k0 += 32) {
    __syncthreads();
    #pragma unroll
    for (int p = 0; p < 8; ++p) {
      const int kk = (tid >> 6) + p*4;
      const int hw = tid & 63;
      lx[kk][hw] = xb[(size_t)(k0+kk)*NPIX + hw];
    }
    #pragma unroll
    for (int p = 0; p < 24; ++p) {
      const int kk = tid & 31;
      const int oo = (tid >> 5) + p*8;
      lw[kk][oo] = wb[(size_t)oo*DIM + k0 + kk];
    }
    __syncthreads();
    #pragma unroll 8
    for (int k = 0; k < 32; ++k) {
      const float4 xv = *reinterpret_cast<const float4*>(&lx[k][tj*4]);
      const float xa[4] = {xv.x, xv.y, xv.z, xv.w};
      #pragma unroll
      for (int g = 0; g < 3; ++g) {
        const float4 wv = *reinterpret_cast<const float4*>(&lw[k][g*64 + ti*4]);
        const float wa[4] = {wv.x, wv.y, wv.z, wv.w};
        #pragma unroll
        for (int rr = 0; rr < 4; ++rr)
          #pragma unroll
          for (int s = 0; s < 4; ++s)
            acc[g*4+rr][s] = fmaf(wa[rr], xa[s], acc[g*4+rr][s]);
      }
    }
  }

  // epilogue: scatter into windowed layout
  const int h = hw0 / WIMG;          // hw tiles are row-aligned (192 = 3*64)
  const int w0 = hw0 % WIMG;
  const int hy = h >> 4, wy = h & 15;
  float* base = qkv + (size_t)slab * SLABSZ;
  const float* bq = bqkv + slab*DIM;
  #pragma unroll
  for (int g = 0; g < 3; ++g) {
    const int ol0 = g*64 + ti*4;
    const int hd = ol0 >> 5, cc0 = ol0 & 31;
    const float4 bv = *reinterpret_cast<const float4*>(&bq[ol0]);
    #pragma unroll
    for (int s = 0; s < 4; ++s) {
      const int w = w0 + tj*4 + s;
      const int wx = w >> 4, wwi = w & 15;
      const int win = b*NWIN_B + hy*WDq + wx;
      const int t = wy*16 + wwi;
      if (slab == 2) {
        float* p = base + (((size_t)(win*HEADS + hd))*HC + cc0)*NTOK + t;
        p[0*NTOK] = acc[g*4+0][s] + bv.x;
        p[1*NTOK] = acc[g*4+1][s] + bv.y;
        p[2*NTOK] = acc[g*4+2][s] + bv.z;
        p[3*NTOK] = acc[g*4+3][s] + bv.w;
      } else {
        const float4 v4 = make_float4(acc[g*4+0][s] + bv.x, acc[g*4+1][s] + bv.y,
                                      acc[g*4+2][s] + bv.z, acc[g*4+3][s] + bv.w);
        *reinterpret_cast<float4*>(base + (((size_t)(win*HEADS + hd))*NTOK + t)*HC + cc0) = v4;
      }
    }
  }
}

// ---------------------------------------------------------------------------
// K2: windowed attention. One block per (window, head); thread = one q row.
// K/V staged in LDS 64 tokens at a time; online softmax across 4 tiles.
// Writes attn output in pixel layout [b][c][h][w] for K3.
// ---------------------------------------------------------------------------
__global__ __launch_bounds__(256)
void k_attn(const float* __restrict__ qkv, const float* __restrict__ rpe,
            float* __restrict__ attn) {
  const int win = blockIdx.x;
  const int head = blockIdx.y;
  const int q = threadIdx.x;
  __shared__ float lk[64][32];    // [t][c]
  __shared__ float lv[32][64];    // [c][t]
  __shared__ float lrpe[RPE_N];
  const float* qp = qkv + ((size_t)(win*HEADS+head))*NTOK*HC;
  const float* kp = qkv + SLABSZ + ((size_t)(win*HEADS+head))*NTOK*HC;
  const float* vp = qkv + 2*SLABSZ + ((size_t)(win*HEADS+head))*HC*NTOK; // [c][t]

  for (int i = q; i < RPE_N; i += 256) lrpe[i] = rpe[head*RPE_N + i];

  float qr[32];
  #pragma unroll
  for (int i = 0; i < 8; ++i) {
    const float4 v4 = reinterpret_cast<const float4*>(qp)[q*8 + i];
    qr[i*4] = v4.x; qr[i*4+1] = v4.y; qr[i*4+2] = v4.z; qr[i*4+3] = v4.w;
  }
  const int qh = q >> 4, qw = q & 15;
  const float scale = 0.17677669529663687f;   // 1/sqrt(32)
  float m = -INFINITY, l = 0.f;
  float o[32];
  #pragma unroll
  for (int cc = 0; cc < 32; ++cc) o[cc] = 0.f;

  #pragma unroll 1
  for (int t0 = 0; t0 < NTOK; t0 += 64) {
    __syncthreads();
    #pragma unroll
    for (int i = 0; i < 2; ++i) {
      const int lf = i*256 + q;
      reinterpret_cast<float4*>(&lk[0][0])[lf] =
          reinterpret_cast<const float4*>(kp + (size_t)t0*HC)[lf];
    }
    #pragma unroll
    for (int i = 0; i < 2; ++i) {
      const int lf = i*256 + q;
      const int cc = lf >> 4, tt = (lf & 15)*4;
      *reinterpret_cast<float4*>(&lv[cc][tt]) =
          *reinterpret_cast<const float4*>(vp + (size_t)cc*NTOK + t0 + tt);
    }
    __syncthreads();

    float s[64];
    #pragma unroll 8
    for (int kt = 0; kt < 64; ++kt) {
      float acc = 0.f;
      #pragma unroll
      for (int i = 0; i < 8; ++i) {
        const float4 kv = *reinterpret_cast<const float4*>(&lk[kt][i*4]);
        acc = fmaf(qr[i*4+0], kv.x, acc);
        acc = fmaf(qr[i*4+1], kv.y, acc);
        acc = fmaf(qr[i*4+2], kv.z, acc);
        acc = fmaf(qr[i*4+3], kv.w, acc);
      }
      const int kt_g = t0 + kt;
      const int rh = (kt_g >> 4) - qh + 15;
      const int rw = (kt_g & 15) - qw + 15;
      s[kt] = acc*scale + lrpe[rh*31 + rw];
    }
    float mt = s[0];
    #pragma unroll
    for (int kt = 1; kt < 64; ++kt) mt = fmaxf(mt, s[kt]);
    const float mnew = fmaxf(m, mt);
    const float f = __expf(m - mnew);
    l *= f;
    #pragma unroll
    for (int cc = 0; cc < 32; ++cc) o[cc] *= f;
    #pragma unroll
    for (int kt = 0; kt < 64; ++kt) {
      s[kt] = __expf(s[kt] - mnew);
      l += s[kt];
    }
    #pragma unroll 4
    for (int kt4 = 0; kt4 < 16; ++kt4) {
      #pragma unroll
      for (int cc = 0; cc < 32; ++cc) {
        const float4 v4 = *reinterpret_cast<const float4*>(&lv[cc][kt4*4]);
        float a = o[cc];
        a = fmaf(s[kt4*4+0], v4.x, a);
        a = fmaf(s[kt4*4+1], v4.y, a);
        a = fmaf(s[kt4*4+2], v4.z, a);
        a = fmaf(s[kt4*4+3], v4.w, a);
        o[cc] = a;
      }
    }
    m = mnew;
  }

  const float inv = 1.f/l;
  const int b = win / NWIN_B, wl = win % NWIN_B;
  const int h = (wl/WDq)*16 + qh;
  const int w = (wl%WDq)*16 + qw;
  float* ob = attn + ((size_t)b*DIM + head*HC)*NPIX + (size_t)h*WIMG + w;
  #pragma unroll
  for (int cc = 0; cc < 32; ++cc)
    ob[(size_t)cc*NPIX] = o[cc]*inv;
}

// ---------------------------------------------------------------------------
// K3: out = w_out @ attn + b_out. Same tiling as K1, single o-slab of 192,
// coalesced float4 writes into [b][c][h][w].
// ---------------------------------------------------------------------------
__global__ __launch_bounds__(256)
void k_proj(const float* __restrict__ attn, const float* __restrict__ wout,
            const float* __restrict__ bout, float* __restrict__ out) {
  const int hw0 = blockIdx.x * 64;
  const int b = blockIdx.y;
  __shared__ float lw[32][196];
  __shared__ float lx[32][64];
  const int tid = threadIdx.x;
  const int ti = tid & 15;
  const int tj = tid >> 4;
  float acc[12][4];
  #pragma unroll
  for (int r = 0; r < 12; ++r)
    #pragma unroll
    for (int s = 0; s < 4; ++s) acc[r][s] = 0.f;

  const float* xb = attn + (size_t)b*DIM*NPIX + hw0;

  #pragma unroll 1
  for (int k0 = 0; k0 < DIM; k0 += 32) {
    __syncthreads();
    #pragma unroll
    for (int p = 0; p < 8; ++p) {
      const int kk = (tid >> 6) + p*4;
      const int hw = tid & 63;
      lx[kk][hw] = xb[(size_t)(k0+kk)*NPIX + hw];
    }
    #pragma unroll
    for (int p = 0; p < 24; ++p) {
      const int kk = tid & 31;
      const int oo = (tid >> 5) + p*8;
      lw[kk][oo] = wout[(size_t)oo*DIM + k0 + kk];
    }
    __syncthreads();
    #pragma unroll 8
    for (int k = 0; k < 32; ++k) {
      const float4 xv = *reinterpret_cast<const float4*>(&lx[k][tj*4]);
      const float xa[4] = {xv.x, xv.y, xv.z, xv.w};
      #pragma unroll
      for (int g = 0; g < 3; ++g) {
        const float4 wv = *reinterpret_cast<const float4*>(&lw[k][g*64 + ti*4]);
        const float wa[4] = {wv.x, wv.y, wv.z, wv.w};
        #pragma unroll
        for (int rr = 0; rr < 4; ++rr)
          #pragma unroll
          for (int s = 0; s < 4; ++s)
            acc[g*4+rr][s] = fmaf(wa[rr], xa[s], acc[g*4+rr][s]);
      }
    }
  }

  float* ob = out + (size_t)b*DIM*NPIX + hw0 + tj*4;
  #pragma unroll
  for (int g = 0; g < 3; ++g) {
    const int ol0 = g*64 + ti*4;
    const float4 bv = *reinterpret_cast<const float4*>(&bout[ol0]);
    const float bb[4] = {bv.x, bv.y, bv.z, bv.w};
    #pragma unroll
    for (int rr = 0; rr < 4; ++rr) {
      const float4 v4 = make_float4(acc[g*4+rr][0]+bb[rr], acc[g*4+rr][1]+bb[rr],
                                    acc[g*4+rr][2]+bb[rr], acc[g*4+rr][3]+bb[rr]);
      *reinterpret_cast<float4*>(ob + (size_t)(ol0+rr)*NPIX) = v4;
    }
  }
}

extern "C" void kernel_launch(void* const* d_in, const int* in_sizes, int n_in,
                              void* d_out, int out_size, void* d_ws, size_t ws_size,
                              hipStream_t stream) {
  const float* x    = (const float*)d_in[0];
  const float* wqkv = (const float*)d_in[1];
  const float* bqkv = (const float*)d_in[2];
  const float* rpe  = (const float*)d_in[3];
  const float* wout = (const float*)d_in[4];
  const float* bout = (const float*)d_in[5];
  float* out = (float*)d_out;

  float* qkv  = (float*)d_ws;                 // 3 * SLABSZ floats (170 MB)
  float* attn = qkv + 3*SLABSZ;               // 14,155,776 floats (56.6 MB)

  dim3 g1(NPIX/64, 3, BATCH);
  k_qkv<<<g1, 256, 0, stream>>>(x, wqkv, bqkv, qkv);

  dim3 g2(NWIN, HEADS);
  k_attn<<<g2, 256, 0, stream>>>(qkv, rpe, attn);

  dim3 g3(NPIX/64, BATCH);
  k_proj<<<g3, 256, 0, stream>>>(attn, wout, bout, out);
}

// Round 2
// 456.299 us; speedup vs baseline: 2.3513x; 2.3513x over previous
//
#include <hip/hip_runtime.h>
#include <math.h>

#define BATCH 2
#define DIM 192
#define HIMG 192
#define WIMG 192
#define NPIX (HIMG*WIMG)      // 36864
#define HEADS 6
#define HC 32
#define NTOK 256
#define WDq 12
#define NWIN_B 144
#define NWIN (BATCH*NWIN_B)   // 288
#define RPE_N 961
#define SLABSZ ((size_t)NWIN*HEADS*NTOK*HC)   // 14,155,776 elems per q/k/v slab

typedef float f32x4 __attribute__((ext_vector_type(4)));
typedef short s16x8 __attribute__((ext_vector_type(8)));
typedef unsigned short u16;

__device__ __forceinline__ u16 f2bf(float f) {
  union { float f; unsigned u; } cv; cv.f = f;
  unsigned u = cv.u + 0x7fffu + ((cv.u >> 16) & 1u);   // RNE
  return (u16)(u >> 16);
}

// ---------------------------------------------------------------------------
// K1: qkv = w_qkv @ x + b_qkv (fp32 compute), scattered into windowed bf16.
//   q,k slabs: [win][head][t][c] bf16 ; v slab: [win][head][c][t] bf16
// ---------------------------------------------------------------------------
__global__ __launch_bounds__(256)
void k_qkv(const float* __restrict__ x, const float* __restrict__ wqkv,
           const float* __restrict__ bqkv, u16* __restrict__ qkv) {
  const int hw0 = blockIdx.x * 64;
  const int slab = blockIdx.y;
  const int b = blockIdx.z;
  __shared__ float lw[32][196];
  __shared__ float lx[32][64];
  const int tid = threadIdx.x;
  const int ti = tid & 15;
  const int tj = tid >> 4;
  float acc[12][4];
  #pragma unroll
  for (int r = 0; r < 12; ++r)
    #pragma unroll
    for (int s = 0; s < 4; ++s) acc[r][s] = 0.f;

  const float* xb = x + (size_t)b*DIM*NPIX + hw0;
  const float* wb = wqkv + (size_t)slab*DIM*DIM;

  #pragma unroll 1
  for (int k0 = 0; k0 < DIM; k0 += 32) {
    __syncthreads();
    #pragma unroll
    for (int p = 0; p < 8; ++p) {
      const int kk = (tid >> 6) + p*4;
      const int hw = tid & 63;
      lx[kk][hw] = xb[(size_t)(k0+kk)*NPIX + hw];
    }
    #pragma unroll
    for (int p = 0; p < 24; ++p) {
      const int kk = tid & 31;
      const int oo = (tid >> 5) + p*8;
      lw[kk][oo] = wb[(size_t)oo*DIM + k0 + kk];
    }
    __syncthreads();
    #pragma unroll 8
    for (int k = 0; k < 32; ++k) {
      const float4 xv = *reinterpret_cast<const float4*>(&lx[k][tj*4]);
      const float xa[4] = {xv.x, xv.y, xv.z, xv.w};
      #pragma unroll
      for (int g = 0; g < 3; ++g) {
        const float4 wv = *reinterpret_cast<const float4*>(&lw[k][g*64 + ti*4]);
        const float wa[4] = {wv.x, wv.y, wv.z, wv.w};
        #pragma unroll
        for (int rr = 0; rr < 4; ++rr)
          #pragma unroll
          for (int s = 0; s < 4; ++s)
            acc[g*4+rr][s] = fmaf(wa[rr], xa[s], acc[g*4+rr][s]);
      }
    }
  }

  const int h = hw0 / WIMG;
  const int w0 = hw0 % WIMG;
  const int hy = h >> 4, wy = h & 15;
  u16* base = qkv + (size_t)slab * SLABSZ;
  const float* bq = bqkv + slab*DIM;
  #pragma unroll
  for (int g = 0; g < 3; ++g) {
    const int ol0 = g*64 + ti*4;
    const int hd = ol0 >> 5, cc0 = ol0 & 31;
    const float4 bv = *reinterpret_cast<const float4*>(&bq[ol0]);
    #pragma unroll
    for (int s = 0; s < 4; ++s) {
      const int w = w0 + tj*4 + s;
      const int wx = w >> 4, wwi = w & 15;
      const int win = b*NWIN_B + hy*WDq + wx;
      const int t = wy*16 + wwi;
      if (slab == 2) {
        u16* p = base + (((size_t)(win*HEADS + hd))*HC + cc0)*NTOK + t;
        p[0*NTOK] = f2bf(acc[g*4+0][s] + bv.x);
        p[1*NTOK] = f2bf(acc[g*4+1][s] + bv.y);
        p[2*NTOK] = f2bf(acc[g*4+2][s] + bv.z);
        p[3*NTOK] = f2bf(acc[g*4+3][s] + bv.w);
      } else {
        ushort4 v4;
        v4.x = f2bf(acc[g*4+0][s] + bv.x);
        v4.y = f2bf(acc[g*4+1][s] + bv.y);
        v4.z = f2bf(acc[g*4+2][s] + bv.z);
        v4.w = f2bf(acc[g*4+3][s] + bv.w);
        *reinterpret_cast<ushort4*>(base + (((size_t)(win*HEADS + hd))*NTOK + t)*HC + cc0) = v4;
      }
    }
  }
}

// ---------------------------------------------------------------------------
// K2: MFMA flash attention. Block = (win, head), 4 waves x 64 q-rows.
// Swapped QK^T: S^T = mfma(Kfrag, Qfrag) -> q column is lane-local (l&15).
// P feeds PV's B operand in-register; V^T fragments match the token map.
// ---------------------------------------------------------------------------
__global__ __launch_bounds__(256)
void k_attn(const u16* __restrict__ qkv, const float* __restrict__ rpe,
            float* __restrict__ attn) {
  const int win = blockIdx.x;
  const int head = blockIdx.y;
  const int tid = threadIdx.x;
  const int wave = tid >> 6;
  const int lane = tid & 63;
  const int u = lane & 15;
  const int g = lane >> 4;

  __shared__ float lrpe[RPE_N];
  for (int i = tid; i < RPE_N; i += 256) lrpe[i] = rpe[head*RPE_N + i];
  __syncthreads();

  const size_t wh = (size_t)(win*HEADS + head);
  const u16* qp = qkv + wh*NTOK*HC;
  const u16* kp = qkv + SLABSZ + wh*NTOK*HC;
  const u16* vp = qkv + 2*SLABSZ + wh*HC*NTOK;

  // Q fragments (B operand): slot i = Q[wave*64+qt*16+u][g*8+i]
  s16x8 qf[4];
  #pragma unroll
  for (int qt = 0; qt < 4; ++qt)
    qf[qt] = *reinterpret_cast<const s16x8*>(qp + (wave*64 + qt*16 + u)*HC + g*8);

  f32x4 oacc[2][4];
  float m[4], l[4];
  #pragma unroll
  for (int qt = 0; qt < 4; ++qt) {
    m[qt] = -INFINITY; l[qt] = 0.f;
    #pragma unroll
    for (int ct = 0; ct < 2; ++ct) oacc[ct][qt] = (f32x4){0.f,0.f,0.f,0.f};
  }
  const float scale = 0.17677669529663687f;  // 1/sqrt(32)

  #pragma unroll 1
  for (int ch = 0; ch < 8; ++ch) {
    const int t0 = ch*32;
    // K fragments (A operand): slot i = K[t0+tau*16+u][g*8+i]
    const s16x8 kf0 = *reinterpret_cast<const s16x8*>(kp + (t0 + u)*HC + g*8);
    const s16x8 kf1 = *reinterpret_cast<const s16x8*>(kp + (t0 + 16 + u)*HC + g*8);
    // V^T fragments (A operand for PV): slot i = V[t0 + (i>>2)*16 + g*4 + (i&3)][ct*16+u]
    s16x8 vf[2];
    #pragma unroll
    for (int ct = 0; ct < 2; ++ct) {
      const int c = ct*16 + u;
      const ushort4 lo = *reinterpret_cast<const ushort4*>(vp + c*NTOK + t0 + g*4);
      const ushort4 hi = *reinterpret_cast<const ushort4*>(vp + c*NTOK + t0 + 16 + g*4);
      s16x8 v;
      v[0]=(short)lo.x; v[1]=(short)lo.y; v[2]=(short)lo.z; v[3]=(short)lo.w;
      v[4]=(short)hi.x; v[5]=(short)hi.y; v[6]=(short)hi.z; v[7]=(short)hi.w;
      vf[ct] = v;
    }
    const f32x4 zero = {0.f,0.f,0.f,0.f};
    f32x4 s0[4], s1[4];
    #pragma unroll
    for (int qt = 0; qt < 4; ++qt) {
      s0[qt] = __builtin_amdgcn_mfma_f32_16x16x32_bf16(kf0, qf[qt], zero, 0, 0, 0);
      s1[qt] = __builtin_amdgcn_mfma_f32_16x16x32_bf16(kf1, qf[qt], zero, 0, 0, 0);
    }
    #pragma unroll
    for (int qt = 0; qt < 4; ++qt) {
      const int qh = wave*4 + qt;
      // S^T content: lane holds k = t0 + tau*16 + g*4 + r for its q-col (u).
      const float* r0 = &lrpe[(ch*2 + 0 - qh + 15)*31 + g*4 + 15 - u];
      const float* r1 = &lrpe[(ch*2 + 1 - qh + 15)*31 + g*4 + 15 - u];
      float p0[4], p1[4];
      #pragma unroll
      for (int r = 0; r < 4; ++r) {
        p0[r] = fmaf(s0[qt][r], scale, r0[r]);
        p1[r] = fmaf(s1[qt][r], scale, r1[r]);
      }
      float mt = fmaxf(fmaxf(fmaxf(p0[0],p0[1]), fmaxf(p0[2],p0[3])),
                       fmaxf(fmaxf(p1[0],p1[1]), fmaxf(p1[2],p1[3])));
      mt = fmaxf(mt, __shfl_xor(mt, 16));
      mt = fmaxf(mt, __shfl_xor(mt, 32));
      const float mnew = fmaxf(m[qt], mt);
      const float f = __expf(m[qt] - mnew);
      m[qt] = mnew;
      float ls = 0.f;
      #pragma unroll
      for (int r = 0; r < 4; ++r) {
        p0[r] = __expf(p0[r] - mnew); ls += p0[r];
        p1[r] = __expf(p1[r] - mnew); ls += p1[r];
      }
      ls += __shfl_xor(ls, 16);
      ls += __shfl_xor(ls, 32);
      l[qt] = l[qt]*f + ls;
      #pragma unroll
      for (int ct = 0; ct < 2; ++ct)
        #pragma unroll
        for (int r = 0; r < 4; ++r) oacc[ct][qt][r] *= f;
      s16x8 pf;
      pf[0]=(short)f2bf(p0[0]); pf[1]=(short)f2bf(p0[1]);
      pf[2]=(short)f2bf(p0[2]); pf[3]=(short)f2bf(p0[3]);
      pf[4]=(short)f2bf(p1[0]); pf[5]=(short)f2bf(p1[1]);
      pf[6]=(short)f2bf(p1[2]); pf[7]=(short)f2bf(p1[3]);
      oacc[0][qt] = __builtin_amdgcn_mfma_f32_16x16x32_bf16(vf[0], pf, oacc[0][qt], 0, 0, 0);
      oacc[1][qt] = __builtin_amdgcn_mfma_f32_16x16x32_bf16(vf[1], pf, oacc[1][qt], 0, 0, 0);
    }
  }

  // O^T layout: row = c_local = ct*16 + g*4 + r, col = q (= u), q-tile (wave,qt)
  const int b = win / NWIN_B, wl = win % NWIN_B;
  const int h0 = (wl / WDq) * 16;
  const int w = (wl % WDq) * 16 + u;
  #pragma unroll
  for (int qt = 0; qt < 4; ++qt) {
    const float inv = 1.f / l[qt];
    const int h = h0 + wave*4 + qt;
    #pragma unroll
    for (int ct = 0; ct < 2; ++ct)
      #pragma unroll
      for (int r = 0; r < 4; ++r) {
        const int c = head*HC + ct*16 + g*4 + r;
        attn[((size_t)(b*DIM + c))*NPIX + (size_t)h*WIMG + w] = oacc[ct][qt][r]*inv;
      }
  }
}

// ---------------------------------------------------------------------------
// K3: out = w_out @ attn + b_out (fp32), unchanged.
// ---------------------------------------------------------------------------
__global__ __launch_bounds__(256)
void k_proj(const float* __restrict__ attn, const float* __restrict__ wout,
            const float* __restrict__ bout, float* __restrict__ out) {
  const int hw0 = blockIdx.x * 64;
  const int b = blockIdx.y;
  __shared__ float lw[32][196];
  __shared__ float lx[32][64];
  const int tid = threadIdx.x;
  const int ti = tid & 15;
  const int tj = tid >> 4;
  float acc[12][4];
  #pragma unroll
  for (int r = 0; r < 12; ++r)
    #pragma unroll
    for (int s = 0; s < 4; ++s) acc[r][s] = 0.f;

  const float* xb = attn + (size_t)b*DIM*NPIX + hw0;

  #pragma unroll 1
  for (int k0 = 0; k0 < DIM; k0 += 32) {
    __syncthreads();
    #pragma unroll
    for (int p = 0; p < 8; ++p) {
      const int kk = (tid >> 6) + p*4;
      const int hw = tid & 63;
      lx[kk][hw] = xb[(size_t)(k0+kk)*NPIX + hw];
    }
    #pragma unroll
    for (int p = 0; p < 24; ++p) {
      const int kk = tid & 31;
      const int oo = (tid >> 5) + p*8;
      lw[kk][oo] = wout[(size_t)oo*DIM + k0 + kk];
    }
    __syncthreads();
    #pragma unroll 8
    for (int k = 0; k < 32; ++k) {
      const float4 xv = *reinterpret_cast<const float4*>(&lx[k][tj*4]);
      const float xa[4] = {xv.x, xv.y, xv.z, xv.w};
      #pragma unroll
      for (int g = 0; g < 3; ++g) {
        const float4 wv = *reinterpret_cast<const float4*>(&lw[k][g*64 + ti*4]);
        const float wa[4] = {wv.x, wv.y, wv.z, wv.w};
        #pragma unroll
        for (int rr = 0; rr < 4; ++rr)
          #pragma unroll
          for (int s = 0; s < 4; ++s)
            acc[g*4+rr][s] = fmaf(wa[rr], xa[s], acc[g*4+rr][s]);
      }
    }
  }

  float* ob = out + (size_t)b*DIM*NPIX + hw0 + tj*4;
  #pragma unroll
  for (int g = 0; g < 3; ++g) {
    const int ol0 = g*64 + ti*4;
    const float4 bv = *reinterpret_cast<const float4*>(&bout[ol0]);
    const float bb[4] = {bv.x, bv.y, bv.z, bv.w};
    #pragma unroll
    for (int rr = 0; rr < 4; ++rr) {
      const float4 v4 = make_float4(acc[g*4+rr][0]+bb[rr], acc[g*4+rr][1]+bb[rr],
                                    acc[g*4+rr][2]+bb[rr], acc[g*4+rr][3]+bb[rr]);
      *reinterpret_cast<float4*>(ob + (size_t)(ol0+rr)*NPIX) = v4;
    }
  }
}

extern "C" void kernel_launch(void* const* d_in, const int* in_sizes, int n_in,
                              void* d_out, int out_size, void* d_ws, size_t ws_size,
                              hipStream_t stream) {
  const float* x    = (const float*)d_in[0];
  const float* wqkv = (const float*)d_in[1];
  const float* bqkv = (const float*)d_in[2];
  const float* rpe  = (const float*)d_in[3];
  const float* wout = (const float*)d_in[4];
  const float* bout = (const float*)d_in[5];
  float* out = (float*)d_out;

  u16* qkv = (u16*)d_ws;                                  // 3 slabs bf16 (85 MB)
  float* attn = (float*)((char*)d_ws + 3*SLABSZ*sizeof(u16));  // 56.6 MB fp32

  dim3 g1(NPIX/64, 3, BATCH);
  k_qkv<<<g1, 256, 0, stream>>>(x, wqkv, bqkv, qkv);

  dim3 g2(NWIN, HEADS);
  k_attn<<<g2, 256, 0, stream>>>(qkv, rpe, attn);

  dim3 g3(NPIX/64, BATCH);
  k_proj<<<g3, 256, 0, stream>>>(attn, wout, bout, out);
}

// Round 3
// 282.242 us; speedup vs baseline: 3.8013x; 1.6167x over previous
//
#include <hip/hip_runtime.h>
#include <math.h>

#define BATCH 2
#define DIM 192
#define HIMG 192
#define WIMG 192
#define NPIX (HIMG*WIMG)      // 36864
#define NPIXT ((size_t)BATCH*NPIX) // 73728 total pixel rows
#define HEADS 6
#define HC 32
#define NTOK 256
#define WDq 12
#define NWIN_B 144
#define NWIN (BATCH*NWIN_B)   // 288
#define RPE_N 961
#define SLABSZ ((size_t)NWIN*HEADS*NTOK*HC)   // 14,155,776 elems per q/k/v slab
#define XSP_E ((size_t)NPIXT*DIM)             // 14,155,776 u16 per split array
#define WSP_E ((size_t)(3*DIM+DIM)*DIM)       // 147,456 u16 (wqkv rows 0..575, wout 576..767)

typedef float f32x4 __attribute__((ext_vector_type(4)));
typedef short s16x8 __attribute__((ext_vector_type(8)));
typedef unsigned short u16;

__device__ __forceinline__ u16 f2bf(float f) {
  union { float f; unsigned u; } cv; cv.f = f;
  unsigned u = cv.u + 0x7fffu + ((cv.u >> 16) & 1u);   // RNE
  return (u16)(u >> 16);
}
__device__ __forceinline__ float bf2f(u16 h) {
  union { unsigned u; float f; } cv; cv.u = ((unsigned)h) << 16;
  return cv.f;
}
__device__ __forceinline__ void split2(float f, u16& hi, u16& lo) {
  hi = f2bf(f);
  lo = f2bf(f - bf2f(hi));
}

// ---------------------------------------------------------------------------
// T0: transpose+split x [b][c][pix] fp32 -> xT_hi/xT_lo [b*pix][c] u16
// ---------------------------------------------------------------------------
__global__ __launch_bounds__(256)
void k_xsplit(const float* __restrict__ x, u16* __restrict__ xhi, u16* __restrict__ xlo) {
  const size_t P0 = (size_t)blockIdx.x * 64;
  const int b = (int)(P0 / NPIX);
  const int p0 = (int)(P0 % NPIX);
  __shared__ float lds[DIM][65];
  const int tid = threadIdx.x;
  const float* xb = x + (size_t)b*DIM*NPIX + p0;
  #pragma unroll
  for (int i = 0; i < 48; ++i) {
    const int idx = i*256 + tid;
    const int c = idx >> 6, pp = idx & 63;
    lds[c][pp] = xb[(size_t)c*NPIX + pp];
  }
  __syncthreads();
  const int wave = tid >> 6, lane = tid & 63;
  if (lane < 48) {
    const int c0 = lane * 4;
    #pragma unroll
    for (int rr = 0; rr < 16; ++rr) {
      const int p = wave*16 + rr;
      ushort4 vh, vl;
      split2(lds[c0+0][p], vh.x, vl.x);
      split2(lds[c0+1][p], vh.y, vl.y);
      split2(lds[c0+2][p], vh.z, vl.z);
      split2(lds[c0+3][p], vh.w, vl.w);
      const size_t off = (P0 + p)*DIM + c0;
      *reinterpret_cast<ushort4*>(xhi + off) = vh;
      *reinterpret_cast<ushort4*>(xlo + off) = vl;
    }
  }
}

// ---------------------------------------------------------------------------
// T1: split w_qkv (576x192) and w_out (192x192) into hi/lo u16, same layout.
// ---------------------------------------------------------------------------
__global__ __launch_bounds__(256)
void k_wsplit(const float* __restrict__ wqkv, const float* __restrict__ wout,
              u16* __restrict__ whi, u16* __restrict__ wlo) {
  const int gid = blockIdx.x*256 + threadIdx.x;      // 36864 threads
  const size_t e0 = (size_t)gid * 4;
  const float* src = (e0 < (size_t)3*DIM*DIM) ? (wqkv + e0) : (wout + (e0 - (size_t)3*DIM*DIM));
  const float4 f = *reinterpret_cast<const float4*>(src);
  ushort4 vh, vl;
  split2(f.x, vh.x, vl.x);
  split2(f.y, vh.y, vl.y);
  split2(f.z, vh.z, vl.z);
  split2(f.w, vh.w, vl.w);
  *reinterpret_cast<ushort4*>(whi + e0) = vh;
  *reinterpret_cast<ushort4*>(wlo + e0) = vl;
}

// ---------------------------------------------------------------------------
// K1: qkv = w_qkv @ x + b_qkv via bf16x2-split MFMA (3 terms, fp32-accurate).
// Block: 128 pix x 192 o (one slab). 4 waves in 2x2: wave covers 96o x 64pix.
// No LDS: per-lane 16B fragment loads from split arrays (L1/L2).
// Epilogue scatters windowed bf16 slabs (identical layout to round 2).
// ---------------------------------------------------------------------------
__global__ __launch_bounds__(256)
void k_qkv_mfma(const u16* __restrict__ xhi, const u16* __restrict__ xlo,
                const u16* __restrict__ whi, const u16* __restrict__ wlo,
                const float* __restrict__ bqkv, u16* __restrict__ qkv) {
  const size_t P0 = (size_t)blockIdx.x * 128;
  const int slab = blockIdx.y;
  const int tid = threadIdx.x;
  const int wave = tid >> 6, lane = tid & 63;
  const int u = lane & 15, g = lane >> 4;
  const int wr = wave >> 1, wc = wave & 1;   // o-half, pix-half
  const int o_w = wr * 96;
  const int hw_w = wc * 64;

  f32x4 acc[6][4];
  #pragma unroll
  for (int of = 0; of < 6; ++of)
    #pragma unroll
    for (int hf = 0; hf < 4; ++hf) acc[of][hf] = (f32x4){0.f,0.f,0.f,0.f};

  const size_t aRow = (size_t)(slab*DIM + o_w + u)*DIM + g*8;
  const u16* aH = whi + aRow;
  const u16* aL = wlo + aRow;
  const size_t bRow = (P0 + hw_w + u)*DIM + g*8;
  const u16* bH = xhi + bRow;
  const u16* bL = xlo + bRow;

  #pragma unroll 1
  for (int k0 = 0; k0 < DIM; k0 += 32) {
    s16x8 bh[4], bl[4];
    #pragma unroll
    for (int hf = 0; hf < 4; ++hf) {
      bh[hf] = *reinterpret_cast<const s16x8*>(bH + hf*16*DIM + k0);
      bl[hf] = *reinterpret_cast<const s16x8*>(bL + hf*16*DIM + k0);
    }
    #pragma unroll
    for (int of = 0; of < 6; ++of) {
      const s16x8 ah = *reinterpret_cast<const s16x8*>(aH + of*16*DIM + k0);
      const s16x8 al = *reinterpret_cast<const s16x8*>(aL + of*16*DIM + k0);
      #pragma unroll
      for (int hf = 0; hf < 4; ++hf) {
        acc[of][hf] = __builtin_amdgcn_mfma_f32_16x16x32_bf16(ah, bh[hf], acc[of][hf], 0, 0, 0);
        acc[of][hf] = __builtin_amdgcn_mfma_f32_16x16x32_bf16(ah, bl[hf], acc[of][hf], 0, 0, 0);
        acc[of][hf] = __builtin_amdgcn_mfma_f32_16x16x32_bf16(al, bh[hf], acc[of][hf], 0, 0, 0);
      }
    }
  }

  // epilogue: windowed scatter, bf16
  u16* base = qkv + (size_t)slab * SLABSZ;
  const float* bq = bqkv + slab*DIM;
  #pragma unroll
  for (int of = 0; of < 6; ++of) {
    const int ob = o_w + of*16 + g*4;        // 4 consecutive o (+r)
    const int hd = ob >> 5, cc = ob & 31;
    const float4 bias = *reinterpret_cast<const float4*>(bq + ob);
    #pragma unroll
    for (int hf = 0; hf < 4; ++hf) {
      const size_t pix = P0 + hw_w + hf*16 + u;
      const int b = (int)(pix / NPIX);
      const int p = (int)(pix % NPIX);
      const int h = p / WIMG, w = p % WIMG;
      const int win = b*NWIN_B + (h >> 4)*WDq + (w >> 4);
      const int t = (h & 15)*16 + (w & 15);
      const float v0 = acc[of][hf][0] + bias.x;
      const float v1 = acc[of][hf][1] + bias.y;
      const float v2 = acc[of][hf][2] + bias.z;
      const float v3 = acc[of][hf][3] + bias.w;
      if (slab == 2) {
        u16* p2 = base + (((size_t)(win*HEADS + hd))*HC + cc)*NTOK + t;
        p2[0*NTOK] = f2bf(v0);
        p2[1*NTOK] = f2bf(v1);
        p2[2*NTOK] = f2bf(v2);
        p2[3*NTOK] = f2bf(v3);
      } else {
        ushort4 st;
        st.x = f2bf(v0); st.y = f2bf(v1); st.z = f2bf(v2); st.w = f2bf(v3);
        *reinterpret_cast<ushort4*>(base + (((size_t)(win*HEADS + hd))*NTOK + t)*HC + cc) = st;
      }
    }
  }
}

// ---------------------------------------------------------------------------
// K2: MFMA flash attention (validated round 2). Epilogue now writes O as
// split hi/lo u16 into attnT [pix][192] (c-contiguous) for K3's MFMA.
// ---------------------------------------------------------------------------
__global__ __launch_bounds__(256)
void k_attn(const u16* __restrict__ qkv, const float* __restrict__ rpe,
            u16* __restrict__ athi, u16* __restrict__ atlo) {
  const int win = blockIdx.x;
  const int head = blockIdx.y;
  const int tid = threadIdx.x;
  const int wave = tid >> 6;
  const int lane = tid & 63;
  const int u = lane & 15;
  const int g = lane >> 4;

  __shared__ float lrpe[RPE_N];
  for (int i = tid; i < RPE_N; i += 256) lrpe[i] = rpe[head*RPE_N + i];
  __syncthreads();

  const size_t wh = (size_t)(win*HEADS + head);
  const u16* qp = qkv + wh*NTOK*HC;
  const u16* kp = qkv + SLABSZ + wh*NTOK*HC;
  const u16* vp = qkv + 2*SLABSZ + wh*HC*NTOK;

  s16x8 qf[4];
  #pragma unroll
  for (int qt = 0; qt < 4; ++qt)
    qf[qt] = *reinterpret_cast<const s16x8*>(qp + (wave*64 + qt*16 + u)*HC + g*8);

  f32x4 oacc[2][4];
  float m[4], l[4];
  #pragma unroll
  for (int qt = 0; qt < 4; ++qt) {
    m[qt] = -INFINITY; l[qt] = 0.f;
    #pragma unroll
    for (int ct = 0; ct < 2; ++ct) oacc[ct][qt] = (f32x4){0.f,0.f,0.f,0.f};
  }
  const float scale = 0.17677669529663687f;  // 1/sqrt(32)

  #pragma unroll 1
  for (int ch = 0; ch < 8; ++ch) {
    const int t0 = ch*32;
    const s16x8 kf0 = *reinterpret_cast<const s16x8*>(kp + (t0 + u)*HC + g*8);
    const s16x8 kf1 = *reinterpret_cast<const s16x8*>(kp + (t0 + 16 + u)*HC + g*8);
    s16x8 vf[2];
    #pragma unroll
    for (int ct = 0; ct < 2; ++ct) {
      const int c = ct*16 + u;
      const ushort4 lo = *reinterpret_cast<const ushort4*>(vp + c*NTOK + t0 + g*4);
      const ushort4 hi = *reinterpret_cast<const ushort4*>(vp + c*NTOK + t0 + 16 + g*4);
      s16x8 v;
      v[0]=(short)lo.x; v[1]=(short)lo.y; v[2]=(short)lo.z; v[3]=(short)lo.w;
      v[4]=(short)hi.x; v[5]=(short)hi.y; v[6]=(short)hi.z; v[7]=(short)hi.w;
      vf[ct] = v;
    }
    const f32x4 zero = {0.f,0.f,0.f,0.f};
    f32x4 s0[4], s1[4];
    #pragma unroll
    for (int qt = 0; qt < 4; ++qt) {
      s0[qt] = __builtin_amdgcn_mfma_f32_16x16x32_bf16(kf0, qf[qt], zero, 0, 0, 0);
      s1[qt] = __builtin_amdgcn_mfma_f32_16x16x32_bf16(kf1, qf[qt], zero, 0, 0, 0);
    }
    #pragma unroll
    for (int qt = 0; qt < 4; ++qt) {
      const int qh = wave*4 + qt;
      const float* r0 = &lrpe[(ch*2 + 0 - qh + 15)*31 + g*4 + 15 - u];
      const float* r1 = &lrpe[(ch*2 + 1 - qh + 15)*31 + g*4 + 15 - u];
      float p0[4], p1[4];
      #pragma unroll
      for (int r = 0; r < 4; ++r) {
        p0[r] = fmaf(s0[qt][r], scale, r0[r]);
        p1[r] = fmaf(s1[qt][r], scale, r1[r]);
      }
      float mt = fmaxf(fmaxf(fmaxf(p0[0],p0[1]), fmaxf(p0[2],p0[3])),
                       fmaxf(fmaxf(p1[0],p1[1]), fmaxf(p1[2],p1[3])));
      mt = fmaxf(mt, __shfl_xor(mt, 16));
      mt = fmaxf(mt, __shfl_xor(mt, 32));
      const float mnew = fmaxf(m[qt], mt);
      const float f = __expf(m[qt] - mnew);
      m[qt] = mnew;
      float ls = 0.f;
      #pragma unroll
      for (int r = 0; r < 4; ++r) {
        p0[r] = __expf(p0[r] - mnew); ls += p0[r];
        p1[r] = __expf(p1[r] - mnew); ls += p1[r];
      }
      ls += __shfl_xor(ls, 16);
      ls += __shfl_xor(ls, 32);
      l[qt] = l[qt]*f + ls;
      #pragma unroll
      for (int ct = 0; ct < 2; ++ct)
        #pragma unroll
        for (int r = 0; r < 4; ++r) oacc[ct][qt][r] *= f;
      s16x8 pf;
      pf[0]=(short)f2bf(p0[0]); pf[1]=(short)f2bf(p0[1]);
      pf[2]=(short)f2bf(p0[2]); pf[3]=(short)f2bf(p0[3]);
      pf[4]=(short)f2bf(p1[0]); pf[5]=(short)f2bf(p1[1]);
      pf[6]=(short)f2bf(p1[2]); pf[7]=(short)f2bf(p1[3]);
      oacc[0][qt] = __builtin_amdgcn_mfma_f32_16x16x32_bf16(vf[0], pf, oacc[0][qt], 0, 0, 0);
      oacc[1][qt] = __builtin_amdgcn_mfma_f32_16x16x32_bf16(vf[1], pf, oacc[1][qt], 0, 0, 0);
    }
  }

  // epilogue: O^T frag (c rows, q cols) -> attnT [pix][c] split hi/lo
  const int b = win / NWIN_B, wl = win % NWIN_B;
  const int h0 = (wl / WDq) * 16;
  const int w = (wl % WDq) * 16 + u;
  #pragma unroll
  for (int qt = 0; qt < 4; ++qt) {
    const float inv = 1.f / l[qt];
    const int h = h0 + wave*4 + qt;
    const size_t row = (size_t)b*NPIX + (size_t)h*WIMG + w;
    #pragma unroll
    for (int ct = 0; ct < 2; ++ct) {
      const int c0 = head*HC + ct*16 + g*4;
      ushort4 vh, vl4;
      split2(oacc[ct][qt][0]*inv, vh.x, vl4.x);
      split2(oacc[ct][qt][1]*inv, vh.y, vl4.y);
      split2(oacc[ct][qt][2]*inv, vh.z, vl4.z);
      split2(oacc[ct][qt][3]*inv, vh.w, vl4.w);
      *reinterpret_cast<ushort4*>(athi + row*DIM + c0) = vh;
      *reinterpret_cast<ushort4*>(atlo + row*DIM + c0) = vl4;
    }
  }
}

// ---------------------------------------------------------------------------
// K3: out = w_out @ attn + b_out via bf16x2-split MFMA. Same structure as K1.
// ---------------------------------------------------------------------------
__global__ __launch_bounds__(256)
void k_proj_mfma(const u16* __restrict__ athi, const u16* __restrict__ atlo,
                 const u16* __restrict__ whi, const u16* __restrict__ wlo,
                 const float* __restrict__ bout, float* __restrict__ out) {
  const size_t P0 = (size_t)blockIdx.x * 128;
  const int tid = threadIdx.x;
  const int wave = tid >> 6, lane = tid & 63;
  const int u = lane & 15, g = lane >> 4;
  const int wr = wave >> 1, wc = wave & 1;
  const int o_w = wr * 96;
  const int hw_w = wc * 64;

  f32x4 acc[6][4];
  #pragma unroll
  for (int of = 0; of < 6; ++of)
    #pragma unroll
    for (int hf = 0; hf < 4; ++hf) acc[of][hf] = (f32x4){0.f,0.f,0.f,0.f};

  const size_t aRow = (size_t)(3*DIM + o_w + u)*DIM + g*8;   // w_out rows at 576
  const u16* aH = whi + aRow;
  const u16* aL = wlo + aRow;
  const size_t bRow = (P0 + hw_w + u)*DIM + g*8;
  const u16* bH = athi + bRow;
  const u16* bL = atlo + bRow;

  #pragma unroll 1
  for (int k0 = 0; k0 < DIM; k0 += 32) {
    s16x8 bh[4], bl[4];
    #pragma unroll
    for (int hf = 0; hf < 4; ++hf) {
      bh[hf] = *reinterpret_cast<const s16x8*>(bH + hf*16*DIM + k0);
      bl[hf] = *reinterpret_cast<const s16x8*>(bL + hf*16*DIM + k0);
    }
    #pragma unroll
    for (int of = 0; of < 6; ++of) {
      const s16x8 ah = *reinterpret_cast<const s16x8*>(aH + of*16*DIM + k0);
      const s16x8 al = *reinterpret_cast<const s16x8*>(aL + of*16*DIM + k0);
      #pragma unroll
      for (int hf = 0; hf < 4; ++hf) {
        acc[of][hf] = __builtin_amdgcn_mfma_f32_16x16x32_bf16(ah, bh[hf], acc[of][hf], 0, 0, 0);
        acc[of][hf] = __builtin_amdgcn_mfma_f32_16x16x32_bf16(ah, bl[hf], acc[of][hf], 0, 0, 0);
        acc[of][hf] = __builtin_amdgcn_mfma_f32_16x16x32_bf16(al, bh[hf], acc[of][hf], 0, 0, 0);
      }
    }
  }

  #pragma unroll
  for (int of = 0; of < 6; ++of) {
    const int ob = o_w + of*16 + g*4;
    const float4 bias = *reinterpret_cast<const float4*>(bout + ob);
    const float bb[4] = {bias.x, bias.y, bias.z, bias.w};
    #pragma unroll
    for (int hf = 0; hf < 4; ++hf) {
      const size_t pix = P0 + hw_w + hf*16 + u;
      const int b = (int)(pix / NPIX);
      const int p = (int)(pix % NPIX);
      #pragma unroll
      for (int r = 0; r < 4; ++r)
        out[((size_t)(b*DIM + ob + r))*NPIX + p] = acc[of][hf][r] + bb[r];
    }
  }
}

extern "C" void kernel_launch(void* const* d_in, const int* in_sizes, int n_in,
                              void* d_out, int out_size, void* d_ws, size_t ws_size,
                              hipStream_t stream) {
  const float* x    = (const float*)d_in[0];
  const float* wqkv = (const float*)d_in[1];
  const float* bqkv = (const float*)d_in[2];
  const float* rpe  = (const float*)d_in[3];
  const float* wout = (const float*)d_in[4];
  const float* bout = (const float*)d_in[5];
  float* out = (float*)d_out;

  u16* xhi  = (u16*)d_ws;
  u16* xlo  = xhi + XSP_E;
  u16* whi  = xlo + XSP_E;
  u16* wlo  = whi + WSP_E;
  u16* qkv  = wlo + WSP_E;            // 3 * SLABSZ bf16
  u16* athi = qkv + 3*SLABSZ;
  u16* atlo = athi + XSP_E;
  // total: 7*XSP_E + 2*WSP_E u16 = 198.8 MB

  k_xsplit<<<dim3(NPIXT/64), 256, 0, stream>>>(x, xhi, xlo);
  k_wsplit<<<dim3(144), 256, 0, stream>>>(wqkv, wout, whi, wlo);

  dim3 g1(NPIXT/128, 3);
  k_qkv_mfma<<<g1, 256, 0, stream>>>(xhi, xlo, whi, wlo, bqkv, qkv);

  dim3 g2(NWIN, HEADS);
  k_attn<<<g2, 256, 0, stream>>>(qkv, rpe, athi, atlo);

  k_proj_mfma<<<dim3(NPIXT/128), 256, 0, stream>>>(athi, atlo, whi, wlo, bout, out);
}